// Round 1
// baseline (165.344 us; speedup 1.0000x reference)
//
#include <hip/hip_runtime.h>

#define PATCH 32

// ---------------------------------------------------------------------------
// Kernel 1: per-patch gate + softmax + top-2 + level, and block-level count
// scan. 256 patches per block (one thread per patch), x staged via LDS with
// +1-pad (stride 33) so per-thread reads are bank-conflict-free.
// ---------------------------------------------------------------------------
__global__ __launch_bounds__(256) void k_gate(
    const float* __restrict__ x, const float* __restrict__ Wg,
    float* __restrict__ w0o, float* __restrict__ w1o,
    int* __restrict__ meta, int* __restrict__ lstart,
    int* __restrict__ blockSums)
{
    __shared__ float sx[256 * 33];
    __shared__ float sw[128];
    __shared__ int   sc[256];
    const int tid = threadIdx.x;
    const long base = (long)blockIdx.x * (256 * PATCH);

    for (int k = tid; k < 256 * PATCH; k += 256)
        sx[(k >> 5) * 33 + (k & 31)] = x[base + k];
    if (tid < 128) sw[tid] = Wg[tid];
    __syncthreads();

    const float* xp = &sx[tid * 33];
    float z0 = 0.f, z1 = 0.f, z2 = 0.f, z3 = 0.f;
    #pragma unroll
    for (int i = 0; i < 32; i++) {
        const float xv = xp[i];
        z0 = fmaf(xv, sw[i],      z0);
        z1 = fmaf(xv, sw[32 + i], z1);
        z2 = fmaf(xv, sw[64 + i], z2);
        z3 = fmaf(xv, sw[96 + i], z3);
    }
    const float zm = fmaxf(fmaxf(z0, z1), fmaxf(z2, z3));
    const float e0 = expf(z0 - zm), e1 = expf(z1 - zm),
                e2 = expf(z2 - zm), e3 = expf(z3 - zm);
    const float s = e0 + e1 + e2 + e3;
    float pv[4];
    pv[0] = e0 / s; pv[1] = e1 / s; pv[2] = e2 / s; pv[3] = e3 / s;

    // top-2, ties -> smaller index (stable descending order)
    int b0 = 0; float v0 = pv[0];
    #pragma unroll
    for (int i = 1; i < 4; i++) if (pv[i] > v0) { v0 = pv[i]; b0 = i; }
    int b1 = -1; float v1 = -1.f;
    #pragma unroll
    for (int i = 0; i < 4; i++) if (i != b0 && pv[i] > v1) { v1 = pv[i]; b1 = i; }

    const int m0 = (b0 < 3) ? b0 : -1;
    const int m1 = (b1 < 3) ? b1 : -1;
    int lv = m0 > m1 ? m0 : m1;
    if (lv < 0) lv = 0;
    const int cnt = 1 << lv;

    const int gp = blockIdx.x * 256 + tid;
    w0o[gp] = v0;                       // ROUTE_SCALE == 1
    w1o[gp] = v1;
    meta[gp] = b0 | (b1 << 4) | (lv << 8);

    // inclusive Hillis-Steele scan of counts over the block
    sc[tid] = cnt;
    __syncthreads();
    for (int off = 1; off < 256; off <<= 1) {
        const int t = (tid >= off) ? sc[tid - off] : 0;
        __syncthreads();
        sc[tid] += t;
        __syncthreads();
    }
    lstart[gp] = sc[tid] - cnt;
    if (tid == 255) blockSums[blockIdx.x] = sc[255];
}

// ---------------------------------------------------------------------------
// Kernel 2: exclusive scan of the per-block sums (n <= 256).
// ---------------------------------------------------------------------------
__global__ __launch_bounds__(256) void k_scan(
    const int* __restrict__ blockSums, int* __restrict__ blockOffs, int n)
{
    __shared__ int sc[256];
    const int tid = threadIdx.x;
    const int own = (tid < n) ? blockSums[tid] : 0;
    sc[tid] = own;
    __syncthreads();
    for (int off = 1; off < 256; off <<= 1) {
        const int t = (tid >= off) ? sc[tid - off] : 0;
        __syncthreads();
        sc[tid] += t;
        __syncthreads();
    }
    if (tid < n) blockOffs[tid] = sc[tid] - own;
}

// ---------------------------------------------------------------------------
// Kernel 3: one wave per patch; emit all outputs for its 2^v children.
// Child rows are contiguous, so every store stream is coalesced.
// ---------------------------------------------------------------------------
__global__ __launch_bounds__(64) void k_emit(
    const float* __restrict__ x, const float* __restrict__ mask,
    const float* __restrict__ w0o, const float* __restrict__ w1o,
    const int* __restrict__ meta, const int* __restrict__ lstart,
    const int* __restrict__ blockOffs,
    float* __restrict__ o_newx, float* __restrict__ o_newm,
    float* __restrict__ o_size, float* __restrict__ o_w,
    float* __restrict__ o_eidx, float* __restrict__ o_xf)
{
    const int p = blockIdx.x;
    const int lane = threadIdx.x;
    __shared__ float shx[32], shm[32], shxm[32];
    if (lane < 32) {
        const float xv = x[(long)p * 32 + lane];
        const float mv = mask[(long)p * 32 + lane];
        shx[lane] = xv; shm[lane] = mv; shxm[lane] = xv * mv;
    }
    const int mt = meta[p];
    const int b0 = mt & 15, b1 = (mt >> 4) & 15, v = (mt >> 8) & 15;
    const int cnt = 1 << v, sz = 32 >> v;
    const long T0 = (long)blockOffs[p >> 8] + lstart[p];
    __syncthreads();

    // new_x / new_mask: [cnt, 32], left-aligned gather, zero pad
    const int n = cnt * 32;
    for (int j = lane; j < n; j += 64) {
        const int c = j >> 5, t = j & 31;
        const bool val = t < sz;
        const int src = val ? (c * sz + t) : 0;
        o_newx[T0 * 32 + j] = val ? shx[src] : 0.f;
        o_newm[T0 * 32 + j] = val ? shm[src] : 0.f;
    }

    // x_final: [cnt, LEVELS=3, 32], granularity-masked xg*mg
    const int nf = cnt * 96;
    for (int j = lane; j < nf; j += 64) {
        const int c = j / 96;
        const int rem = j - c * 96;
        const int l = rem >> 5, t = rem & 31;
        float val = 0.f;
        if (l == v) {
            const int lo = c * sz;
            if (t >= lo && t < lo + sz) val = shxm[t];
        } else if (v >= 1 && l == v - 1) {
            const int cp = c >> 1, szp = sz << 1;
            const int lo = cp * szp;
            if (t >= lo && t < lo + szp) val = shxm[t];
        }
        o_xf[T0 * 96 + j] = val;
    }

    if (lane < cnt) o_size[T0 + lane] = (float)sz;
    if (lane < 2 * cnt) {
        const int k = lane & 1;
        o_w[T0 * 2 + lane]    = k ? w1o[p] : w0o[p];
        o_eidx[T0 * 2 + lane] = (float)(k ? b1 : b0);
    }
}

extern "C" void kernel_launch(void* const* d_in, const int* in_sizes, int n_in,
                              void* d_out, int out_size, void* d_ws, size_t ws_size,
                              hipStream_t stream) {
    const float* x    = (const float*)d_in[0];
    const float* mask = (const float*)d_in[1];
    const float* Wg   = (const float*)d_in[2];

    const int  P  = in_sizes[0] / PATCH;   // 65536
    const int  NB = (P + 255) / 256;       // 256
    const long T  = (long)out_size / 165;  // total children, fixed by harness

    char* ws = (char*)d_ws;
    float* w0o = (float*)ws;  ws += (size_t)P * 4;
    float* w1o = (float*)ws;  ws += (size_t)P * 4;
    int*   meta = (int*)ws;   ws += (size_t)P * 4;
    int*   lst  = (int*)ws;   ws += (size_t)P * 4;
    int*   bsum = (int*)ws;   ws += (size_t)NB * 4;
    int*   boff = (int*)ws;

    float* out = (float*)d_out;
    float* o_newx = out;
    float* o_newm = out + T * 32;
    float* o_size = out + T * 64;
    float* o_w    = out + T * 65;
    float* o_eidx = out + T * 67;
    float* o_xf   = out + T * 69;

    hipLaunchKernelGGL(k_gate, dim3(NB), dim3(256), 0, stream,
                       x, Wg, w0o, w1o, meta, lst, bsum);
    hipLaunchKernelGGL(k_scan, dim3(1), dim3(256), 0, stream, bsum, boff, NB);
    hipLaunchKernelGGL(k_emit, dim3(P), dim3(64), 0, stream,
                       x, mask, w0o, w1o, meta, lst, boff,
                       o_newx, o_newm, o_size, o_w, o_eidx, o_xf);
}

// Round 2
// 151.172 us; speedup vs baseline: 1.0937x; 1.0937x over previous
//
#include <hip/hip_runtime.h>

#define PATCH 32

// ---------------------------------------------------------------------------
// Kernel 1: per-patch gate + softmax + top-2 + level, plus in-block count
// scan. One thread per patch; x read directly as 8x float4 per thread.
// ---------------------------------------------------------------------------
__global__ __launch_bounds__(256) void k_gate(
    const float* __restrict__ x, const float* __restrict__ Wg,
    float* __restrict__ w0o, float* __restrict__ w1o,
    int* __restrict__ meta, int* __restrict__ lstart,
    int* __restrict__ blockSums)
{
    __shared__ float sw[128];
    __shared__ int   sc[256];
    const int tid = threadIdx.x;
    if (tid < 128) sw[tid] = Wg[tid];

    const long base = (long)blockIdx.x * (256 * PATCH) + (long)tid * PATCH;
    const float4* xg = (const float4*)(x + base);
    float4 xv[8];
    #pragma unroll
    for (int i = 0; i < 8; i++) xv[i] = xg[i];
    __syncthreads();

    float z0 = 0.f, z1 = 0.f, z2 = 0.f, z3 = 0.f;
    #pragma unroll
    for (int i = 0; i < 8; i++) {
        const float* f = (const float*)&xv[i];
        #pragma unroll
        for (int k = 0; k < 4; k++) {
            const float v = f[k];
            const int i4 = i * 4 + k;
            z0 = fmaf(v, sw[i4],      z0);
            z1 = fmaf(v, sw[32 + i4], z1);
            z2 = fmaf(v, sw[64 + i4], z2);
            z3 = fmaf(v, sw[96 + i4], z3);
        }
    }
    const float zm = fmaxf(fmaxf(z0, z1), fmaxf(z2, z3));
    const float e0 = expf(z0 - zm), e1 = expf(z1 - zm),
                e2 = expf(z2 - zm), e3 = expf(z3 - zm);
    const float s = e0 + e1 + e2 + e3;
    float pv[4];
    pv[0] = e0 / s; pv[1] = e1 / s; pv[2] = e2 / s; pv[3] = e3 / s;

    // top-2, ties -> smaller index
    int b0 = 0; float v0 = pv[0];
    #pragma unroll
    for (int i = 1; i < 4; i++) if (pv[i] > v0) { v0 = pv[i]; b0 = i; }
    int b1 = -1; float v1 = -1.f;
    #pragma unroll
    for (int i = 0; i < 4; i++) if (i != b0 && pv[i] > v1) { v1 = pv[i]; b1 = i; }

    const int m0 = (b0 < 3) ? b0 : -1;
    const int m1 = (b1 < 3) ? b1 : -1;
    int lv = m0 > m1 ? m0 : m1;
    if (lv < 0) lv = 0;
    const int cnt = 1 << lv;

    const int gp = blockIdx.x * 256 + tid;
    w0o[gp] = v0;
    w1o[gp] = v1;
    meta[gp] = b0 | (b1 << 4) | (lv << 8);

    sc[tid] = cnt;
    __syncthreads();
    for (int off = 1; off < 256; off <<= 1) {
        const int t = (tid >= off) ? sc[tid - off] : 0;
        __syncthreads();
        sc[tid] += t;
        __syncthreads();
    }
    lstart[gp] = sc[tid] - cnt;
    if (tid == 255) blockSums[blockIdx.x] = sc[255];
}

// ---------------------------------------------------------------------------
// Kernel 2: each of the 256 blocks redundantly scans the 256 block sums
// (LDS), then one thread per patch emits packed per-child metadata and the
// small output streams (size / weights / expert_idx).
// packed childMeta: p<<8 | b0<<6 | b1<<4 | c<<2 | v
// ---------------------------------------------------------------------------
__global__ __launch_bounds__(256) void k_mid(
    const int* __restrict__ blockSums,
    const float* __restrict__ w0o, const float* __restrict__ w1o,
    const int* __restrict__ meta, const int* __restrict__ lstart,
    int* __restrict__ childMeta,
    float* __restrict__ o_size, float* __restrict__ o_w,
    float* __restrict__ o_eidx)
{
    __shared__ int sscan[256];
    __shared__ int sOff;
    const int tid = threadIdx.x;
    const int own = blockSums[tid];
    sscan[tid] = own;
    __syncthreads();
    for (int off = 1; off < 256; off <<= 1) {
        const int t = (tid >= off) ? sscan[tid - off] : 0;
        __syncthreads();
        sscan[tid] += t;
        __syncthreads();
    }
    if (tid == blockIdx.x) sOff = sscan[tid] - own;   // exclusive prefix for this block
    __syncthreads();

    const int p = blockIdx.x * 256 + tid;
    const int mt = meta[p];
    const int b0 = mt & 15, b1 = (mt >> 4) & 15, v = (mt >> 8) & 15;
    const int cnt = 1 << v, sz = PATCH >> v;
    const long T0 = (long)sOff + lstart[p];
    const float w0 = w0o[p], w1 = w1o[p];
    const int packed = (p << 8) | (b0 << 6) | (b1 << 4) | v;
    const float fsz = (float)sz, fb0 = (float)b0, fb1 = (float)b1;
    for (int c = 0; c < cnt; c++) {
        const long r = T0 + c;
        childMeta[r] = packed | (c << 2);
        o_size[r] = fsz;
        o_w[r * 2]     = w0;  o_w[r * 2 + 1]     = w1;
        o_eidx[r * 2]  = fb0; o_eidx[r * 2 + 1]  = fb1;
    }
}

// ---------------------------------------------------------------------------
// Kernel 3: row-centric emit. 32 child rows per 256-thread block; every
// store is a dense coalesced float4 (valid regions are float4-aligned since
// sz in {8,16,32}).
// ---------------------------------------------------------------------------
__global__ __launch_bounds__(256) void k_emit(
    const float* __restrict__ x, const float* __restrict__ mask,
    const int* __restrict__ childMeta, const long T,
    float4* __restrict__ o_newx, float4* __restrict__ o_newm,
    float4* __restrict__ o_xf)
{
    __shared__ int smeta[32];
    const int tid = threadIdx.x;
    const long R0 = (long)blockIdx.x * 32;
    if (tid < 32) smeta[tid] = (R0 + tid < T) ? childMeta[R0 + tid] : 0;
    __syncthreads();

    // new_x / new_mask: 32 rows x 8 float4
    {
        const int j = tid >> 3, q = tid & 7;
        const long r = R0 + j;
        if (r < T) {
            const int m = smeta[j];
            const int p = m >> 8, c = (m >> 2) & 3, v = m & 3;
            const int sz = PATCH >> v;
            float4 vx = {0.f, 0.f, 0.f, 0.f}, vm = {0.f, 0.f, 0.f, 0.f};
            if (4 * q < sz) {
                const long src = (long)p * PATCH + c * sz + 4 * q;
                vx = *(const float4*)(x + src);
                vm = *(const float4*)(mask + src);
            }
            o_newx[r * 8 + q] = vx;
            o_newm[r * 8 + q] = vm;
        }
    }

    // x_final: 32 rows x 3 levels x 8 float4 = 768 float4 per block
    #pragma unroll
    for (int it = 0; it < 3; it++) {
        const int f = it * 256 + tid;        // 0..767
        const int j = f / 24;                // row in block
        const int rem = f - j * 24;
        const int l = rem >> 3, q = rem & 7;
        const long r = R0 + j;
        if (r < T) {
            const int m = smeta[j];
            const int p = m >> 8, c = (m >> 2) & 3, v = m & 3;
            const int sz = PATCH >> v;
            const int t4 = 4 * q;
            bool nz = false;
            if (l == v) {
                const int lo = c * sz;
                nz = (t4 >= lo) && (t4 < lo + sz);
            } else if (v >= 1 && l == v - 1) {
                const int cp = c >> 1, szp = sz << 1, lo = cp * szp;
                nz = (t4 >= lo) && (t4 < lo + szp);
            }
            float4 out = {0.f, 0.f, 0.f, 0.f};
            if (nz) {
                const long src = (long)p * PATCH + t4;
                const float4 vx = *(const float4*)(x + src);
                const float4 vm = *(const float4*)(mask + src);
                out.x = vx.x * vm.x; out.y = vx.y * vm.y;
                out.z = vx.z * vm.z; out.w = vx.w * vm.w;
            }
            o_xf[r * 24 + l * 8 + q] = out;
        }
    }
}

extern "C" void kernel_launch(void* const* d_in, const int* in_sizes, int n_in,
                              void* d_out, int out_size, void* d_ws, size_t ws_size,
                              hipStream_t stream) {
    const float* x    = (const float*)d_in[0];
    const float* mask = (const float*)d_in[1];
    const float* Wg   = (const float*)d_in[2];

    const int  P  = in_sizes[0] / PATCH;   // 65536
    const int  NB = (P + 255) / 256;       // 256
    const long T  = (long)out_size / 165;  // total children (fixed inputs)

    char* ws = (char*)d_ws;
    float* w0o  = (float*)ws;  ws += (size_t)P * 4;
    float* w1o  = (float*)ws;  ws += (size_t)P * 4;
    int*   meta = (int*)ws;    ws += (size_t)P * 4;
    int*   lst  = (int*)ws;    ws += (size_t)P * 4;
    int*   bsum = (int*)ws;    ws += (size_t)NB * 4;
    int*   cmeta = (int*)ws;

    float* out = (float*)d_out;
    float* o_newx = out;
    float* o_newm = out + T * 32;
    float* o_size = out + T * 64;
    float* o_w    = out + T * 65;
    float* o_eidx = out + T * 67;
    float* o_xf   = out + T * 69;

    hipLaunchKernelGGL(k_gate, dim3(NB), dim3(256), 0, stream,
                       x, Wg, w0o, w1o, meta, lst, bsum);
    hipLaunchKernelGGL(k_mid, dim3(NB), dim3(256), 0, stream,
                       bsum, w0o, w1o, meta, lst, cmeta, o_size, o_w, o_eidx);
    const int NE = (int)((T + 31) / 32);
    hipLaunchKernelGGL(k_emit, dim3(NE), dim3(256), 0, stream,
                       x, mask, cmeta, T,
                       (float4*)o_newx, (float4*)o_newm, (float4*)o_xf);
}